// Round 6
// baseline (349.470 us; speedup 1.0000x reference)
//
#include <hip/hip_runtime.h>
#include <cstdint>
#include <cstddef>

#define NB 32        // batch
#define NC 256       // channels
#define HW 56        // spatial
#define PLANE (HW*HW)       // 3136
#define NPLANE (NB*NC)      // 8192
#define NHEADS 8
#define HDIM 32
#define NPOOL 64            // 8*8
#define EPSV 1e-5f
#define HALF4 392           // float4 per half-plane (28*56/4)

// ---------------------------------------------------------------------------
// K1: row/col means. Wave-autonomous half-plane slices (6.27 KB/wave,
// 25 KB/block -> 4 blocks/CU, ALL 1024 blocks co-resident, zero tail).
// Pipeline: spill(s) -> prefetch(s+1) -> reduce(s), so next loads fly during
// the LDS reduction. 2 planes/wave, 4 steps (plane,half).
// ---------------------------------------------------------------------------
__global__ __launch_bounds__(256) void k_means(const float* __restrict__ x,
                                               float* __restrict__ hm,
                                               float* __restrict__ wm) {
    __shared__ float sm[4][28 * HW];
    const int wid = threadIdx.x >> 6, lane = threadIdx.x & 63;
    float* myL = sm[wid];
    float4* myL4 = (float4*)myL;
    const int gw = blockIdx.x * 4 + wid;       // 0..4095; planes gw, gw+4096

    float4 buf[7];
    {   // prefetch step 0: (gw, half 0)
        const float4* pb = (const float4*)(x + (size_t)gw * PLANE);
#pragma unroll
        for (int k = 0; k < 6; ++k) buf[k] = pb[k * 64 + lane];
        if (lane < 8) buf[6] = pb[384 + lane];
    }
    float colacc = 0.f;
#pragma unroll
    for (int s = 0; s < 4; ++s) {
        const int p = (s < 2) ? gw : gw + 4096;
        const int h = s & 1;
        // spill current half to my LDS slice (b128, stride-1: conflict-free)
#pragma unroll
        for (int k = 0; k < 6; ++k) myL4[k * 64 + lane] = buf[k];
        if (lane < 8) myL4[384 + lane] = buf[6];
        // prefetch next step while we reduce this one
        if (s < 3) {
            const int pn = (s < 1) ? gw : gw + 4096;
            const int hn = (s + 1) & 1;
            const float4* pb = (const float4*)(x + (size_t)pn * PLANE) + hn * HALF4;
#pragma unroll
            for (int k = 0; k < 6; ++k) buf[k] = pb[k * 64 + lane];
            if (lane < 8) buf[6] = pb[384 + lane];
        }
        // row sums: lane pair (r = lane>>1, part = lane&1), rotated cols for bank spread
        if (lane < 56) {
            int part = lane & 1, r = lane >> 1;      // r in 0..27
            float rs = 0.f;
            int jj = r & 27;                          // rotation start (cheap, <28)
            if (jj >= 28) jj -= 28;
#pragma unroll
            for (int i = 0; i < 28; ++i) {
                rs += myL[r * 56 + part * 28 + jj];
                jj = (jj == 27) ? 0 : jj + 1;
            }
            rs += __shfl_xor(rs, 1);
            if (part == 0) hm[(size_t)p * 56 + h * 28 + r] = rs * (1.f / 56.f);
        }
        // col partial sums: lane = col (fixed r, lanes spread: conflict-free)
        if (lane < 56) {
            float cs = 0.f;
#pragma unroll
            for (int r = 0; r < 28; ++r) cs += myL[r * 56 + lane];
            colacc += cs;
            if (h == 1) {
                wm[(size_t)p * 56 + lane] = colacc * (1.f / 56.f);
                colacc = 0.f;
            }
        }
    }
}

// ---------------------------------------------------------------------------
// K2: sa_branch (depthwise conv + GroupNorm(4) + sigmoid). 64 blocks. (round-2)
// ---------------------------------------------------------------------------
__global__ __launch_bounds__(256) void k_branch(
    const float* __restrict__ hm, const float* __restrict__ wm,
    const float* __restrict__ w3, const float* __restrict__ b3,
    const float* __restrict__ w5, const float* __restrict__ b5,
    const float* __restrict__ w7, const float* __restrict__ b7,
    const float* __restrict__ w9, const float* __restrict__ b9,
    const float* __restrict__ hsc, const float* __restrict__ hbi,
    const float* __restrict__ wsc, const float* __restrict__ wbi,
    float* __restrict__ hattn, float* __restrict__ wattn) {
    int mode = blockIdx.x & 1;
    int b = blockIdx.x >> 1;
    const float* src = (mode == 0 ? hm : wm) + (size_t)b * NC * 56;
    const float* scale = (mode == 0 ? hsc : wsc);
    const float* bias = (mode == 0 ? hbi : wbi);
    float* dst = (mode == 0 ? hattn : wattn) + (size_t)b * NC * 56;

    __shared__ float sm[NC * 57];
    int t = threadIdx.x;
    const float4* sp = (const float4*)src;
#pragma unroll
    for (int k = 0; k < 14; ++k) {
        int f = t + 256 * k;
        float4 v = sp[f];
        int c = f / 14, r = f - c * 14;
        float* d = &sm[c * 57 + r * 4];
        d[0] = v.x; d[1] = v.y; d[2] = v.z; d[3] = v.w;
    }
    __syncthreads();

    int c = t;
    int g = c >> 6, cc = c & 63;
    float wc[9];
#pragma unroll
    for (int i = 0; i < 9; ++i) wc[i] = 0.f;
    float bb = 0.f;
    if (g == 0) {
#pragma unroll
        for (int q = 0; q < 3; ++q) wc[3 + q] = w3[cc * 3 + q];
        bb = b3[cc];
    } else if (g == 1) {
#pragma unroll
        for (int q = 0; q < 5; ++q) wc[2 + q] = w5[cc * 5 + q];
        bb = b5[cc];
    } else if (g == 2) {
#pragma unroll
        for (int q = 0; q < 7; ++q) wc[1 + q] = w7[cc * 7 + q];
        bb = b7[cc];
    } else {
#pragma unroll
        for (int q = 0; q < 9; ++q) wc[q] = w9[cc * 9 + q];
        bb = b9[cc];
    }

    float xv[56];
#pragma unroll
    for (int i = 0; i < 56; ++i) xv[i] = sm[c * 57 + i];

    float s1 = 0.f, s2 = 0.f;
#pragma unroll
    for (int i = 0; i < 56; ++i) {
        float a = bb;
#pragma unroll
        for (int d = 0; d < 9; ++d) {
            int j = i + d - 4;
            if (j >= 0 && j < 56) a += wc[d] * xv[j];
        }
        s1 += a;
        s2 += a * a;
    }
#pragma unroll
    for (int off = 32; off >= 1; off >>= 1) {
        s1 += __shfl_xor(s1, off);
        s2 += __shfl_xor(s2, off);
    }
    float mean = s1 * (1.f / 3584.f);
    float var = s2 * (1.f / 3584.f) - mean * mean;
    float rstd = rsqrtf(var + EPSV);
    float scv = scale[c];
    float a_lin = scv * rstd;
    float b_lin = bias[c] - mean * rstd * scv;
#pragma unroll
    for (int i = 0; i < 56; ++i) {
        float a = bb;
#pragma unroll
        for (int d = 0; d < 9; ++d) {
            int j = i + d - 4;
            if (j >= 0 && j < 56) a += wc[d] * xv[j];
        }
        float v = a * a_lin + b_lin;
        sm[c * 57 + i] = 1.f / (1.f + expf(-v));
    }
    __syncthreads();
    float4* dp = (float4*)dst;
#pragma unroll
    for (int k = 0; k < 14; ++k) {
        int f = t + 256 * k;
        int c2 = f / 14, r = f - c2 * 14;
        const float* s = &sm[c2 * 57 + r * 4];
        dp[f] = make_float4(s[0], s[1], s[2], s[3]);
    }
}

// ---------------------------------------------------------------------------
// K3: gated 7x7 avgpool -> ypool. Same half-plane pipelined structure as K1.
// Half h covers pooled rows 4h..4h+3 exactly (28 rows). Reduce uses all 64
// lanes: (cell = lane>>1, sub = lane&1), sub splits dh 0-3 / 4-6.
// Pool read pattern 8*il + 7*j mod 32 is a perfect permutation: conflict-free.
// ---------------------------------------------------------------------------
__global__ __launch_bounds__(256) void k_pool(const float* __restrict__ x,
                                              const float* __restrict__ hattn,
                                              const float* __restrict__ wattn,
                                              float* __restrict__ ypool) {
    __shared__ float sm[4][28 * HW];
    __shared__ float gg[4][112];               // [0:56) ha, [56:112) wa
    const int wid = threadIdx.x >> 6, lane = threadIdx.x & 63;
    float* myL = sm[wid];
    float4* myL4 = (float4*)myL;
    float* myG = gg[wid];
    const int gw = blockIdx.x * 4 + wid;

    float4 buf[7];
    float ghv = 0.f, gwv = 0.f;
    {
        const float4* pb = (const float4*)(x + (size_t)gw * PLANE);
#pragma unroll
        for (int k = 0; k < 6; ++k) buf[k] = pb[k * 64 + lane];
        if (lane < 8) buf[6] = pb[384 + lane];
        if (lane < 56) {
            ghv = hattn[(size_t)gw * 56 + lane];
            gwv = wattn[(size_t)gw * 56 + lane];
        }
    }
#pragma unroll
    for (int s = 0; s < 4; ++s) {
        const int p = (s < 2) ? gw : gw + 4096;
        const int h = s & 1;
        // spill x half
#pragma unroll
        for (int k = 0; k < 6; ++k) myL4[k * 64 + lane] = buf[k];
        if (lane < 8) myL4[384 + lane] = buf[6];
        // publish gates at start of each plane
        if (h == 0 && lane < 56) { myG[lane] = ghv; myG[56 + lane] = gwv; }
        // prefetch next x half
        if (s < 3) {
            const int pn = (s < 1) ? gw : gw + 4096;
            const int hn = (s + 1) & 1;
            const float4* pb = (const float4*)(x + (size_t)pn * PLANE) + hn * HALF4;
#pragma unroll
            for (int k = 0; k < 6; ++k) buf[k] = pb[k * 64 + lane];
            if (lane < 8) buf[6] = pb[384 + lane];
        }
        // prefetch next plane's gates
        if (s == 1 && lane < 56) {
            ghv = hattn[(size_t)(gw + 4096) * 56 + lane];
            gwv = wattn[(size_t)(gw + 4096) * 56 + lane];
        }
        // reduce: 32 cells, 2 lanes each
        {
            int sub = lane & 1, cell = lane >> 1;   // cell 0..31
            int il = cell >> 3, j = cell & 7;       // il 0..3, j 0..7
            float sacc = 0.f;
#pragma unroll
            for (int d2 = 0; d2 < 4; ++d2) {
                int dh = sub * 4 + d2;
                if (dh < 7) {
                    int r = il * 7 + dh;            // local row 0..27
                    float rr = 0.f;
#pragma unroll
                    for (int dw = 0; dw < 7; ++dw)
                        rr += myL[r * 56 + 7 * j + dw] * myG[56 + 7 * j + dw];
                    sacc += myG[h * 28 + r] * rr;
                }
            }
            sacc += __shfl_xor(sacc, 1);
            if (sub == 0)
                ypool[(size_t)p * NPOOL + (h * 4 + il) * 8 + j] = sacc * (1.f / 49.f);
        }
    }
}

// ---------------------------------------------------------------------------
// K4: per-(b,head) attention -> channel gate ca (GN1 stats in-block). (round-2)
// ---------------------------------------------------------------------------
__global__ __launch_bounds__(64) void k_attn(const float* __restrict__ ypool,
                                             const float* __restrict__ nsc,
                                             const float* __restrict__ nbi,
                                             const float* __restrict__ qw,
                                             const float* __restrict__ kw,
                                             const float* __restrict__ vw,
                                             float* __restrict__ ca) {
    int bh = blockIdx.x;
    int b = bh >> 3, h = bh & 7;
    int l = threadIdx.x;
    const float4* bp = (const float4*)(ypool + (size_t)b * NC * NPOOL);
    float s1 = 0.f, s2 = 0.f;
#pragma unroll
    for (int k = 0; k < 64; ++k) {
        float4 v = bp[l + 64 * k];
        s1 += v.x + v.y + v.z + v.w;
        s2 += v.x * v.x + v.y * v.y + v.z * v.z + v.w * v.w;
    }
#pragma unroll
    for (int off = 32; off >= 1; off >>= 1) {
        s1 += __shfl_xor(s1, off);
        s2 += __shfl_xor(s2, off);
    }
    float mean = s1 * (1.f / (NC * NPOOL));
    float var = s2 * (1.f / (NC * NPOOL)) - mean * mean;
    float rstd = rsqrtf(var + EPSV);

    __shared__ float yn[32][65];
    __shared__ float ybar[32];
    __shared__ float G[32][33];
    const float* base = ypool + ((size_t)b * NC + h * HDIM) * NPOOL;
#pragma unroll
    for (int m = 0; m < 32; ++m) {
        int idx = l + 64 * m;
        int d = idx >> 6, p = idx & 63;
        int ch = h * HDIM + d;
        float v = base[idx];
        yn[d][p] = (v - mean) * rstd * nsc[ch] + nbi[ch];
    }
    __syncthreads();
    if (l < 32) {
        float s = 0.f;
#pragma unroll
        for (int p = 0; p < 64; ++p) s += yn[l][p];
        ybar[l] = s * (1.f / 64.f);
    }
    __syncthreads();
#pragma unroll
    for (int m = 0; m < 16; ++m) {
        int idx = l + 64 * m;
        int d = idx >> 5, e = idx & 31;
        float s = 0.f;
#pragma unroll
        for (int p = 0; p < 64; ++p) s += yn[d][p] * yn[e][p];
        G[d][e] = s;
    }
    __syncthreads();
    if (l < 32) {
        int d = l, cd = h * HDIM + d;
        float qs = qw[cd] * 0.17677669529663687f;   // 1/sqrt(32)
        float a[32];
        float mx = -1e30f;
#pragma unroll
        for (int e = 0; e < 32; ++e) {
            a[e] = G[d][e] * qs * kw[h * HDIM + e];
            mx = fmaxf(mx, a[e]);
        }
        float sum = 0.f;
#pragma unroll
        for (int e = 0; e < 32; ++e) {
            a[e] = expf(a[e] - mx);
            sum += a[e];
        }
        float o = 0.f;
#pragma unroll
        for (int e = 0; e < 32; ++e) o += a[e] * vw[h * HDIM + e] * ybar[e];
        o /= sum;
        ca[b * NC + cd] = 1.f / (1.f + expf(-o));
    }
}

// ---------------------------------------------------------------------------
// K5: out = x * hattn * wattn * ca. Wave-autonomous, barrier-free.
// Gates in a 512 B wave LDS slice; wv fetched as aligned ds_read_b128.
// 1024 blocks (4/CU, all resident), 2 planes/wave.
// ---------------------------------------------------------------------------
__global__ __launch_bounds__(256) void k_final(const float* __restrict__ x,
                                               const float* __restrict__ hattn,
                                               const float* __restrict__ wattn,
                                               const float* __restrict__ ca,
                                               float* __restrict__ out) {
    __shared__ float gg[4][128];            // [0:56) hv*ca, [64:120) wv
    const int wid = threadIdx.x >> 6, lane = threadIdx.x & 63;
    float* myG = gg[wid];
    const int gw = blockIdx.x * 4 + wid;

#pragma unroll
    for (int s = 0; s < 2; ++s) {
        const int plane = gw + s * 4096;
        float cav = ca[plane];
        if (lane < 56) {
            myG[lane] = hattn[(size_t)plane * 56 + lane] * cav;
            myG[64 + lane] = wattn[(size_t)plane * 56 + lane];
        }
        const float4* xp = (const float4*)(x + (size_t)plane * PLANE);
        float4* op = (float4*)(out + (size_t)plane * PLANE);
        float4 buf[13];
#pragma unroll
        for (int k = 0; k < 12; ++k) buf[k] = xp[k * 64 + lane];
        if (lane < 16) buf[12] = xp[768 + lane];
#pragma unroll
        for (int k = 0; k < 12; ++k) {
            int f = k * 64 + lane;
            int r = f / 14, s0 = (f - r * 14) * 4;
            float hf = myG[r];
            float4 w4 = *(const float4*)&myG[64 + s0];   // aligned b128
            float4 v = buf[k];
            v.x *= hf * w4.x;
            v.y *= hf * w4.y;
            v.z *= hf * w4.z;
            v.w *= hf * w4.w;
            op[f] = v;
        }
        if (lane < 16) {
            int f = 768 + lane;
            int r = f / 14, s0 = (f - r * 14) * 4;
            float hf = myG[r];
            float4 w4 = *(const float4*)&myG[64 + s0];
            float4 v = buf[12];
            v.x *= hf * w4.x;
            v.y *= hf * w4.y;
            v.z *= hf * w4.z;
            v.w *= hf * w4.w;
            op[f] = v;
        }
    }
}

extern "C" void kernel_launch(void* const* d_in, const int* in_sizes, int n_in,
                              void* d_out, int out_size, void* d_ws, size_t ws_size,
                              hipStream_t stream) {
    const float* x   = (const float*)d_in[0];
    const float* w3  = (const float*)d_in[1];
    const float* b3  = (const float*)d_in[2];
    const float* w5  = (const float*)d_in[3];
    const float* b5  = (const float*)d_in[4];
    const float* w7  = (const float*)d_in[5];
    const float* b7  = (const float*)d_in[6];
    const float* w9  = (const float*)d_in[7];
    const float* b9  = (const float*)d_in[8];
    const float* hsc = (const float*)d_in[9];
    const float* hbi = (const float*)d_in[10];
    const float* wsc = (const float*)d_in[11];
    const float* wbi = (const float*)d_in[12];
    const float* nsc = (const float*)d_in[13];
    const float* nbi = (const float*)d_in[14];
    const float* qw  = (const float*)d_in[15];
    const float* kw  = (const float*)d_in[16];
    const float* vw  = (const float*)d_in[17];
    float* out = (float*)d_out;

    float* ws    = (float*)d_ws;
    float* hm    = ws;
    float* wm    = hm + (size_t)NPLANE * 56;
    float* hattn = wm + (size_t)NPLANE * 56;
    float* wattn = hattn + (size_t)NPLANE * 56;
    float* ypool = wattn + (size_t)NPLANE * 56;
    float* ca    = ypool + (size_t)NPLANE * NPOOL;

    k_means<<<1024, 256, 0, stream>>>(x, hm, wm);
    k_branch<<<2 * NB, 256, 0, stream>>>(hm, wm, w3, b3, w5, b5, w7, b7, w9, b9,
                                         hsc, hbi, wsc, wbi, hattn, wattn);
    k_pool<<<1024, 256, 0, stream>>>(x, hattn, wattn, ypool);
    k_attn<<<NB * NHEADS, 64, 0, stream>>>(ypool, nsc, nbi, qw, kw, vw, ca);
    k_final<<<1024, 256, 0, stream>>>(x, hattn, wattn, ca, out);
}